// Round 3
// baseline (10932.776 us; speedup 1.0000x reference)
//
#include <hip/hip_runtime.h>

// ---------------------------------------------------------------------------
// 2-layer LSTM (B=64, T=256, D=512, H1=H2=1024) + dense head.
// R3: persistent cooperative kernel.
//   - 256 blocks x 256 threads, 1 block/CU (137 KiB dynamic LDS forces it).
//   - Block b<128: layer1, owns units b*8..b*8+7 (32 gate-cols, K=1536).
//     Block b>=128: layer2, same for units (b-128)*8.. (K=2048).
//   - Weights transposed to bf16 [col][K] at setup, loaded into LDS ONCE.
//   - 257 supersteps separated by a sense-reversing device-scope grid barrier
//     (all blocks co-resident: grid == CU count, LDS caps 1 block/CU).
//   - A-fragments read straight from global (16B contiguous in 16x16x32
//     A-layout); cell state lives in 2 registers/thread across all steps.
// ---------------------------------------------------------------------------

typedef __bf16 bf16x8 __attribute__((ext_vector_type(8)));
typedef float f32x4 __attribute__((ext_vector_type(4)));

#define LDS_W_BYTES   131584   // 32 rows * (2048+8) bf16 * 2B (worst case, L2)
#define LDS_Z_OFF     131584   // Zlds: 64*33 f32 = 8448 B
#define LDS_B_OFF     140032   // bias: 32 f32 = 128 B
#define LDS_TOTAL     140160

__device__ __forceinline__ unsigned short f2bf(float f) {
  unsigned u = __float_as_uint(f);
  unsigned r = (u + 0x7FFFu + ((u >> 16) & 1u)) >> 16;  // RNE (finite inputs)
  return (unsigned short)r;
}

// in: fp32 [R][C] row-major  ->  out: bf16 [C][R] row-major (i.e. B^T layout)
__global__ __launch_bounds__(256) void transpose_to_bf16(
    const float* __restrict__ in, unsigned short* __restrict__ out, int R, int C) {
  __shared__ float tile[32][33];
  int tx = threadIdx.x & 31, ty = threadIdx.x >> 5;  // 32 x 8
  int c0 = blockIdx.x * 32, r0 = blockIdx.y * 32;
#pragma unroll
  for (int i = 0; i < 4; ++i)
    tile[ty + i * 8][tx] = in[(size_t)(r0 + ty + i * 8) * C + (c0 + tx)];
  __syncthreads();
#pragma unroll
  for (int i = 0; i < 4; ++i)
    out[(size_t)(c0 + ty + i * 8) * R + (r0 + tx)] = f2bf(tile[tx][ty + i * 8]);
}

__global__ __launch_bounds__(256) void convert_to_bf16(
    const float* __restrict__ in, unsigned short* __restrict__ out, int n4) {
  int i = blockIdx.x * 256 + threadIdx.x;
  if (i >= n4) return;
  float4 v = reinterpret_cast<const float4*>(in)[i];
  ushort4 o;
  o.x = f2bf(v.x); o.y = f2bf(v.y); o.z = f2bf(v.z); o.w = f2bf(v.w);
  reinterpret_cast<ushort4*>(out)[i] = o;
}

__global__ void init_bar(unsigned* __restrict__ bar) { bar[threadIdx.x] = 0u; }

// Sense-free grid barrier: arrive-counter + monotonically increasing epoch.
// Safe because epoch `want` is unique per step. Device-scope (cross-XCD).
__device__ __forceinline__ void grid_barrier(unsigned* __restrict__ arrive,
                                             unsigned* __restrict__ epoch,
                                             unsigned want) {
  __syncthreads();  // drains all waves' vmem (s_waitcnt vmcnt(0) before s_barrier)
  if (threadIdx.x == 0) {
    __threadfence();  // release: block's stores -> visible device-wide
    unsigned old = __hip_atomic_fetch_add(arrive, 1u, __ATOMIC_ACQ_REL,
                                          __HIP_MEMORY_SCOPE_AGENT);
    if (old == 255u) {
      __hip_atomic_store(arrive, 0u, __ATOMIC_RELAXED, __HIP_MEMORY_SCOPE_AGENT);
      __hip_atomic_store(epoch, want, __ATOMIC_RELEASE, __HIP_MEMORY_SCOPE_AGENT);
    } else {
      while (__hip_atomic_load(epoch, __ATOMIC_ACQUIRE,
                               __HIP_MEMORY_SCOPE_AGENT) != want)
        __builtin_amdgcn_s_sleep(2);
    }
    __threadfence();  // acquire side: invalidate L1/L2 before consuming h
  }
  __syncthreads();
}

__global__ __launch_bounds__(256, 1) void lstm_persistent(
    const unsigned short* __restrict__ xbf,   // [64][256][512] bf16
    const unsigned short* __restrict__ W1t,   // [4096][512]
    const unsigned short* __restrict__ U1t,   // [4096][1024]
    const float* __restrict__ b1,
    const unsigned short* __restrict__ W2t,   // [4096][1024]
    const unsigned short* __restrict__ U2t,   // [4096][1024]
    const float* __restrict__ b2,
    unsigned short* __restrict__ h1r,         // [2][64][1024] bf16
    unsigned short* __restrict__ h2r,         // [2][64][1024] bf16
    unsigned* __restrict__ bar)               // [256]: [0]=arrive, [64]=epoch
{
  extern __shared__ __align__(16) char smem[];
  const int blk = blockIdx.x;
  const bool is2 = blk >= 128;
  const int lb  = is2 ? blk - 128 : blk;
  const int u0  = lb * 8;                 // first owned unit
  const int K   = is2 ? 2048 : 1536;
  const int pitch = K + 8;                // +8 bf16 pad: rows -> 2-way banks (free)
  unsigned short* Wlds = (unsigned short*)smem;          // [32][pitch]
  float* Zlds = (float*)(smem + LDS_Z_OFF);              // [64][33]
  float* Blds = (float*)(smem + LDS_B_OFF);              // [32] bias

  const int tid = threadIdx.x;

  // ---- one-time: weight slice -> LDS (row r: gate r>>3, unit u0+(r&7)) ----
  {
    const int r = tid >> 3, sub = tid & 7;               // 32 rows x 8 threads
    const int c = (r >> 3) * 1024 + u0 + (r & 7);        // global gate-col
    const unsigned short* wsrc;
    const unsigned short* usrc;
    int wk;
    if (is2) { wsrc = W2t + (size_t)c * 1024; usrc = U2t + (size_t)c * 1024; wk = 1024; }
    else     { wsrc = W1t + (size_t)c * 512;  usrc = U1t + (size_t)c * 1024; wk = 512;  }
    unsigned short* dst = Wlds + r * pitch;
    for (int k = sub * 8; k < wk; k += 64)
      *(uint4*)(dst + k) = *(const uint4*)(wsrc + k);
    for (int k = sub * 8; k < 1024; k += 64)
      *(uint4*)(dst + wk + k) = *(const uint4*)(usrc + k);
    if (tid < 32) {
      const float* bias = is2 ? b2 : b1;
      Blds[tid] = bias[(tid >> 3) * 1024 + u0 + (tid & 7)];
    }
  }
  __syncthreads();

  const int wave = tid >> 6, lane = tid & 63;
  const int quad = lane >> 4, l16 = lane & 15;
  const int m = wave * 16 + l16;                         // batch row (A)
  const unsigned short* Bp0 = Wlds + l16 * pitch + quad * 8;         // col-tile 0
  const unsigned short* Bp1 = Wlds + (16 + l16) * pitch + quad * 8;  // col-tile 1

  // persistent cell state: thread owns (b=tid>>3, u=tid&7) and (b+32, u)
  const int eb = tid >> 3, eu = tid & 7;
  float cLo = 0.f, cHi = 0.f;
  const float bz0 = Blds[eu], bz1 = Blds[8 + eu], bz2 = Blds[16 + eu],
              bz3 = Blds[24 + eu];

  for (int s = 0; s <= 256; ++s) {
    const int t = is2 ? (s - 1) : s;
    if (t >= 0 && t < 256) {
      f32x4 acc0 = {0.f, 0.f, 0.f, 0.f}, acc1 = {0.f, 0.f, 0.f, 0.f};
      if (!is2) {
        // segment 1: x_t (K 0..511)
        const unsigned short* ax = xbf + ((size_t)m * 256 + t) * 512 + quad * 8;
#pragma unroll
        for (int ks = 0; ks < 16; ++ks) {
          bf16x8 a  = *(const bf16x8*)(ax + ks * 32);
          bf16x8 w0 = *(const bf16x8*)(Bp0 + ks * 32);
          bf16x8 w1 = *(const bf16x8*)(Bp1 + ks * 32);
          acc0 = __builtin_amdgcn_mfma_f32_16x16x32_bf16(a, w0, acc0, 0, 0, 0);
          acc1 = __builtin_amdgcn_mfma_f32_16x16x32_bf16(a, w1, acc1, 0, 0, 0);
        }
        // segment 2: h1_{t-1} (K 512..1535)
        if (t > 0) {
          const unsigned short* ah =
              h1r + (size_t)((t - 1) & 1) * 65536 + (size_t)m * 1024 + quad * 8;
#pragma unroll
          for (int ks = 0; ks < 32; ++ks) {
            bf16x8 a  = *(const bf16x8*)(ah + ks * 32);
            bf16x8 w0 = *(const bf16x8*)(Bp0 + 512 + ks * 32);
            bf16x8 w1 = *(const bf16x8*)(Bp1 + 512 + ks * 32);
            acc0 = __builtin_amdgcn_mfma_f32_16x16x32_bf16(a, w0, acc0, 0, 0, 0);
            acc1 = __builtin_amdgcn_mfma_f32_16x16x32_bf16(a, w1, acc1, 0, 0, 0);
          }
        }
      } else {
        // segment 1: h1_t (K 0..1023)
        const unsigned short* ah1 =
            h1r + (size_t)(t & 1) * 65536 + (size_t)m * 1024 + quad * 8;
#pragma unroll
        for (int ks = 0; ks < 32; ++ks) {
          bf16x8 a  = *(const bf16x8*)(ah1 + ks * 32);
          bf16x8 w0 = *(const bf16x8*)(Bp0 + ks * 32);
          bf16x8 w1 = *(const bf16x8*)(Bp1 + ks * 32);
          acc0 = __builtin_amdgcn_mfma_f32_16x16x32_bf16(a, w0, acc0, 0, 0, 0);
          acc1 = __builtin_amdgcn_mfma_f32_16x16x32_bf16(a, w1, acc1, 0, 0, 0);
        }
        // segment 2: h2_{t-1} (K 1024..2047)
        if (t > 0) {
          const unsigned short* ah2 =
              h2r + (size_t)((t - 1) & 1) * 65536 + (size_t)m * 1024 + quad * 8;
#pragma unroll
          for (int ks = 0; ks < 32; ++ks) {
            bf16x8 a  = *(const bf16x8*)(ah2 + ks * 32);
            bf16x8 w0 = *(const bf16x8*)(Bp0 + 1024 + ks * 32);
            bf16x8 w1 = *(const bf16x8*)(Bp1 + 1024 + ks * 32);
            acc0 = __builtin_amdgcn_mfma_f32_16x16x32_bf16(a, w0, acc0, 0, 0, 0);
            acc1 = __builtin_amdgcn_mfma_f32_16x16x32_bf16(a, w1, acc1, 0, 0, 0);
          }
        }
      }

      // exchange z across waves: C/D layout col=lane&15, row=quad*4+i
#pragma unroll
      for (int i = 0; i < 4; ++i) {
        Zlds[(wave * 16 + quad * 4 + i) * 33 + l16]      = acc0[i];
        Zlds[(wave * 16 + quad * 4 + i) * 33 + 16 + l16] = acc1[i];
      }
      __syncthreads();

      unsigned short* hring = is2 ? h2r : h1r;
      const size_t hbase = (size_t)(t & 1) * 65536 + u0 + eu;
      {
        float zi = Zlds[eb * 33 + eu]      + bz0;
        float zf = Zlds[eb * 33 + 8 + eu]  + bz1;
        float zg = Zlds[eb * 33 + 16 + eu] + bz2;
        float zo = Zlds[eb * 33 + 24 + eu] + bz3;
        float ig = 1.f / (1.f + __expf(-zi));
        float fg = 1.f / (1.f + __expf(-zf));
        float gg = 1.f - 2.f / (1.f + __expf(2.f * zg));
        float og = 1.f / (1.f + __expf(-zo));
        cLo = fg * cLo + ig * gg;
        float h = og * (1.f - 2.f / (1.f + __expf(2.f * cLo)));
        hring[hbase + (size_t)eb * 1024] = f2bf(h);
      }
      {
        int b2r = eb + 32;
        float zi = Zlds[b2r * 33 + eu]      + bz0;
        float zf = Zlds[b2r * 33 + 8 + eu]  + bz1;
        float zg = Zlds[b2r * 33 + 16 + eu] + bz2;
        float zo = Zlds[b2r * 33 + 24 + eu] + bz3;
        float ig = 1.f / (1.f + __expf(-zi));
        float fg = 1.f / (1.f + __expf(-zf));
        float gg = 1.f - 2.f / (1.f + __expf(2.f * zg));
        float og = 1.f / (1.f + __expf(-zo));
        cHi = fg * cHi + ig * gg;
        float h = og * (1.f - 2.f / (1.f + __expf(2.f * cHi)));
        hring[hbase + (size_t)b2r * 1024] = f2bf(h);
      }
    }
    if (s < 256) grid_barrier(&bar[0], &bar[64], (unsigned)(s + 1));
  }
}

// out[64][512] = h2_last @ Wd + bd.  One wave per 16x16 tile, K=1024.
__global__ __launch_bounds__(64) void dense_kernel(
    const unsigned short* __restrict__ h2,   // [64][1024] bf16
    const unsigned short* __restrict__ Wdt,  // [512][1024] bf16
    const float* __restrict__ bd,
    float* __restrict__ out) {
  int mt = blockIdx.x >> 5;  // 0..3
  int nt = blockIdx.x & 31;  // 0..31
  int lane = threadIdx.x;
  int quad = lane >> 4, l16 = lane & 15;
  f32x4 acc = {0.f, 0.f, 0.f, 0.f};
  const unsigned short* ap = h2 + (size_t)(mt * 16 + l16) * 1024 + quad * 8;
  const unsigned short* bp = Wdt + (size_t)(nt * 16 + l16) * 1024 + quad * 8;
#pragma unroll
  for (int ks = 0; ks < 32; ++ks) {
    bf16x8 a = *reinterpret_cast<const bf16x8*>(ap + ks * 32);
    bf16x8 b = *reinterpret_cast<const bf16x8*>(bp + ks * 32);
    acc = __builtin_amdgcn_mfma_f32_16x16x32_bf16(a, b, acc, 0, 0, 0);
  }
  int colo = nt * 16 + l16;
  float bias = bd[colo];
#pragma unroll
  for (int i = 0; i < 4; ++i)
    out[(size_t)(mt * 16 + quad * 4 + i) * 512 + colo] = acc[i] + bias;
}

extern "C" void kernel_launch(void* const* d_in, const int* in_sizes, int n_in,
                              void* d_out, int out_size, void* d_ws, size_t ws_size,
                              hipStream_t stream) {
  const float* x  = (const float*)d_in[0];
  const float* W1 = (const float*)d_in[1];
  const float* U1 = (const float*)d_in[2];
  const float* b1 = (const float*)d_in[3];
  const float* W2 = (const float*)d_in[4];
  const float* U2 = (const float*)d_in[5];
  const float* b2 = (const float*)d_in[6];
  const float* Wd = (const float*)d_in[7];
  const float* bd = (const float*)d_in[8];
  float* out = (float*)d_out;

  char* p = (char*)d_ws;
  auto carve = [&](size_t bytes) -> char* {
    char* r = p;
    p += (bytes + 255) & ~(size_t)255;
    return r;
  };
  // ~45.5 MiB total (R2's 46 MiB budget passed; R1's 78 MiB overflowed ws)
  unsigned short* W1t = (unsigned short*)carve((size_t)4096 * 512 * 2);
  unsigned short* U1t = (unsigned short*)carve((size_t)4096 * 1024 * 2);
  unsigned short* W2t = (unsigned short*)carve((size_t)4096 * 1024 * 2);
  unsigned short* U2t = (unsigned short*)carve((size_t)4096 * 1024 * 2);
  unsigned short* Wdt = (unsigned short*)carve((size_t)512 * 1024 * 2);
  unsigned short* xbf = (unsigned short*)carve((size_t)64 * 256 * 512 * 2);
  unsigned short* h1r = (unsigned short*)carve((size_t)2 * 64 * 1024 * 2);
  unsigned short* h2r = (unsigned short*)carve((size_t)2 * 64 * 1024 * 2);
  unsigned* bar = (unsigned*)carve(256 * 4);
  (void)ws_size; (void)in_sizes; (void)n_in; (void)out_size;

  transpose_to_bf16<<<dim3(128, 16), 256, 0, stream>>>(W1, W1t, 512, 4096);
  transpose_to_bf16<<<dim3(128, 32), 256, 0, stream>>>(U1, U1t, 1024, 4096);
  transpose_to_bf16<<<dim3(128, 32), 256, 0, stream>>>(W2, W2t, 1024, 4096);
  transpose_to_bf16<<<dim3(128, 32), 256, 0, stream>>>(U2, U2t, 1024, 4096);
  transpose_to_bf16<<<dim3(16, 32), 256, 0, stream>>>(Wd, Wdt, 1024, 512);
  convert_to_bf16<<<8192, 256, 0, stream>>>(x, xbf, 64 * 256 * 512 / 4);
  init_bar<<<1, 256, 0, stream>>>(bar);

  // idempotent, host-side only (not a stream op) -> graph-capture safe
  hipFuncSetAttribute(reinterpret_cast<const void*>(lstm_persistent),
                      hipFuncAttributeMaxDynamicSharedMemorySize, LDS_TOTAL);
  lstm_persistent<<<256, 256, LDS_TOTAL, stream>>>(
      xbf, W1t, U1t, b1, W2t, U2t, b2, h1r, h2r, bar);

  dense_kernel<<<128, 64, 0, stream>>>(h2r + 65536, Wdt, bd, out);
}